// Round 3
// baseline (217.073 us; speedup 1.0000x reference)
//
#include <hip/hip_runtime.h>
#include <cstdint>
#include <cstddef>

#define N_INST 8192
#define L_DIM  384
#define D_DIM  128
#define C_CLS  5

typedef __bf16 bf16x8 __attribute__((ext_vector_type(8)));
typedef float  f32x4  __attribute__((ext_vector_type(4)));

typedef __attribute__((address_space(1))) void gvoid_t;
typedef __attribute__((address_space(3))) void lvoid_t;

__device__ __forceinline__ unsigned short f2bf(float f) {
  unsigned u = __float_as_uint(f);
  unsigned r = (u + 0x7FFFu + ((u >> 16) & 1u)) >> 16;  // RNE
  return (unsigned short)r;
}
__device__ __forceinline__ float bf2f(unsigned short b) {
  return __uint_as_float(((unsigned)b) << 16);
}

__device__ __forceinline__ void gload_lds16(const void* g, void* lds) {
  __builtin_amdgcn_global_load_lds(
      (gvoid_t*)(uintptr_t)g,
      (lvoid_t*)(uint32_t)(uintptr_t)lds,
      16, 0, 0);
}

// ---- prep: x -> bf16, sq[i] = sum(bf16(x_i)^2) in fp32 -------------------
__global__ __launch_bounds__(256) void prep_x_kernel(
    const float* __restrict__ x, unsigned short* __restrict__ xbf,
    float* __restrict__ sq) {
  int w = threadIdx.x >> 6, lane = threadIdx.x & 63;
  int row = blockIdx.x * 4 + w;
  const float* xr = x + (size_t)row * L_DIM;
  unsigned short* br = xbf + (size_t)row * L_DIM;
  float s = 0.f;
#pragma unroll
  for (int k = 0; k < 6; ++k) {
    float v = xr[lane + 64 * k];
    unsigned short b = f2bf(v);
    br[lane + 64 * k] = b;
    float vb = bf2f(b);
    s = fmaf(vb, vb, s);
  }
#pragma unroll
  for (int off = 32; off; off >>= 1) s += __shfl_down(s, off, 64);
  if (lane == 0) sq[row] = s;
}

// ---- prep: aW1 [384][128] -> aW1T_bf [128][384] --------------------------
__global__ __launch_bounds__(256) void prep_w_kernel(
    const float* __restrict__ aW1, unsigned short* __restrict__ w1t) {
  int idx = blockIdx.x * 256 + threadIdx.x;  // 49152 total
  int d = idx / L_DIM, l = idx - d * L_DIM;
  w1t[idx] = f2bf(aW1[(size_t)l * D_DIM + d]);
}

// ---- attention GEMM: h_tanh[i][d] = tanh(x_bf . aW1T[d] + ab1[d]) --------
__global__ __launch_bounds__(256, 2) void attn_gemm_kernel(
    const unsigned short* __restrict__ amat,   // x_bf [8192][384]
    const unsigned short* __restrict__ bmat,   // aW1T_bf [128][384]
    const float* __restrict__ bias,            // ab1
    float* __restrict__ out) {
  __shared__ alignas(16) unsigned short As[128][64];
  __shared__ alignas(16) unsigned short Bs[128][64];

  int tid = threadIdx.x;
  int w = tid >> 6, lane = tid & 63;
  int wr = w >> 1, wc = w & 1;
  int i0 = blockIdx.x * 128;

  const unsigned short* asrc = amat + (size_t)i0 * L_DIM;
  const unsigned short* bsrc = bmat;

  f32x4 acc[4][4];
#pragma unroll
  for (int m = 0; m < 4; ++m)
#pragma unroll
    for (int n = 0; n < 4; ++n) acc[m][n] = (f32x4){0.f, 0.f, 0.f, 0.f};

  int lrow = lane & 15, lkb = lane >> 4;

  for (int kc = 0; kc < 6; ++kc) {
    int k0 = kc * 64;
#pragma unroll
    for (int c = 0; c < 4; ++c) {
      int rb = c * 32 + w * 8;
      gload_lds16(asrc + (size_t)(rb + (lane >> 3)) * L_DIM + k0 + (lane & 7) * 8,
                  &As[rb][0]);
      gload_lds16(bsrc + (size_t)(rb + (lane >> 3)) * L_DIM + k0 + (lane & 7) * 8,
                  &Bs[rb][0]);
    }
    __syncthreads();
#pragma unroll
    for (int kk = 0; kk < 64; kk += 32) {
      bf16x8 af[4], bfr[4];
#pragma unroll
      for (int m = 0; m < 4; ++m)
        af[m] = *(const bf16x8*)&As[wr * 64 + m * 16 + lrow][kk + lkb * 8];
#pragma unroll
      for (int n = 0; n < 4; ++n)
        bfr[n] = *(const bf16x8*)&Bs[wc * 64 + n * 16 + lrow][kk + lkb * 8];
#pragma unroll
      for (int m = 0; m < 4; ++m)
#pragma unroll
        for (int n = 0; n < 4; ++n)
          acc[m][n] = __builtin_amdgcn_mfma_f32_16x16x32_bf16(
              bfr[n], af[m], acc[m][n], 0, 0, 0);  // swapped operands
    }
    __syncthreads();
  }
  // i = i0 + wr*64 + m*16 + lrow ; d = wc*64 + n*16 + lkb*4 + r
#pragma unroll
  for (int m = 0; m < 4; ++m) {
    int gi = i0 + wr * 64 + m * 16 + lrow;
    float* orow = out + (size_t)gi * D_DIM;
#pragma unroll
    for (int n = 0; n < 4; ++n) {
      int d0 = wc * 64 + n * 16 + lkb * 4;
      f32x4 bv = *(const f32x4*)&bias[d0];
      f32x4 o;
#pragma unroll
      for (int r = 0; r < 4; ++r) o[r] = tanhf(acc[m][n][r] + bv[r]);
      *(f32x4*)&orow[d0] = o;  // workspace, 16B aligned
    }
  }
}

// ---- dist GEMM: upper-tri tiles, LDS-staged aligned epilogue -------------
// dist[i][j] = sqrt(max(sq_i+sq_j-2*dot,0)) at F[5 + i*8192 + j], diag = 0.
// acc[m][n][r] = dot(i_local, j_local):
//   i_local = wr*64 + m*16 + lrow ; j_local = wc*64 + n*16 + lkb*4 + r
__global__ __launch_bounds__(256, 2) void dist_kernel(
    const unsigned short* __restrict__ xbf, const float* __restrict__ sqv,
    float* __restrict__ F) {
  __shared__ alignas(16) unsigned short As[128][64];
  __shared__ alignas(16) unsigned short Bs[128][64];
  __shared__ alignas(16) float T[64][132];  // 528B row stride (16B multiple)

  int b = blockIdx.x;
  // map b -> upper-tri (ti, tj), row ti has 64-ti tiles; C(t) = t*(129-t)/2
  int ti = (int)((129.0 - sqrt(129.0 * 129.0 - 8.0 * (double)b)) * 0.5);
  while ((ti + 1) * (129 - (ti + 1)) / 2 <= b) ++ti;
  while (ti * (129 - ti) / 2 > b) --ti;
  int tj = ti + (b - ti * (129 - ti) / 2);
  int i0 = ti * 128, j0 = tj * 128;

  int tid = threadIdx.x;
  int w = tid >> 6, lane = tid & 63;
  int wr = w >> 1, wc = w & 1;
  int lrow = lane & 15, lkb = lane >> 4;

  const unsigned short* asrc = xbf + (size_t)i0 * L_DIM;
  const unsigned short* bsrc = xbf + (size_t)j0 * L_DIM;

  f32x4 acc[4][4];
#pragma unroll
  for (int m = 0; m < 4; ++m)
#pragma unroll
    for (int n = 0; n < 4; ++n) acc[m][n] = (f32x4){0.f, 0.f, 0.f, 0.f};

  for (int kc = 0; kc < 6; ++kc) {
    int k0 = kc * 64;
#pragma unroll
    for (int c = 0; c < 4; ++c) {
      int rb = c * 32 + w * 8;
      gload_lds16(asrc + (size_t)(rb + (lane >> 3)) * L_DIM + k0 + (lane & 7) * 8,
                  &As[rb][0]);
      gload_lds16(bsrc + (size_t)(rb + (lane >> 3)) * L_DIM + k0 + (lane & 7) * 8,
                  &Bs[rb][0]);
    }
    __syncthreads();
#pragma unroll
    for (int kk = 0; kk < 64; kk += 32) {
      bf16x8 af[4], bfr[4];
#pragma unroll
      for (int m = 0; m < 4; ++m)
        af[m] = *(const bf16x8*)&As[wr * 64 + m * 16 + lrow][kk + lkb * 8];
#pragma unroll
      for (int n = 0; n < 4; ++n)
        bfr[n] = *(const bf16x8*)&Bs[wc * 64 + n * 16 + lrow][kk + lkb * 8];
#pragma unroll
      for (int m = 0; m < 4; ++m)
#pragma unroll
        for (int n = 0; n < 4; ++n)
          acc[m][n] = __builtin_amdgcn_mfma_f32_16x16x32_bf16(
              bfr[n], af[m], acc[m][n], 0, 0, 0);
    }
    __syncthreads();
  }

  int rgrp = tid >> 5, k = tid & 31;

  // ---- normal direction: 2 chunks of 64 rows ----
#pragma unroll
  for (int chunk = 0; chunk < 2; ++chunk) {
#pragma unroll
    for (int mlo = 0; mlo < 2; ++mlo) {
      int m = chunk * 2 + mlo;
      int gi = i0 + wr * 64 + m * 16 + lrow;
      float si = sqv[gi];
      int t = wr * 32 + mlo * 16 + lrow;
#pragma unroll
      for (int n = 0; n < 4; ++n) {
        int jl = wc * 64 + n * 16 + lkb * 4;
        f32x4 sj = *(const f32x4*)&sqv[j0 + jl];
        f32x4 o;
#pragma unroll
        for (int r = 0; r < 4; ++r) {
          float d2 = si + sj[r] - 2.f * acc[m][n][r];
          float dv = (d2 > 0.f) ? sqrtf(d2) : 0.f;
          if (gi == j0 + jl + r) dv = 0.f;
          o[r] = dv;
        }
        *(f32x4*)&T[t][jl] = o;
      }
    }
    __syncthreads();
    // cooperative aligned row writes: rows gi, cols j0..j0+127
#pragma unroll
    for (int it = 0; it < 8; ++it) {
      int t = it * 8 + rgrp;
      int gi = i0 + (t >> 5) * 64 + chunk * 32 + (t & 31);
      float* row = F + 5 + (size_t)gi * N_INST + j0;
      if (k < 31) {
        int jj = 3 + 4 * k;  // element index (5+gi*8192+j0+jj) % 4 == 0
        f32x4 v;
        v[0] = T[t][jj]; v[1] = T[t][jj + 1];
        v[2] = T[t][jj + 2]; v[3] = T[t][jj + 3];
        *(f32x4*)&row[jj] = v;
      } else {
        row[0] = T[t][0]; row[1] = T[t][1]; row[2] = T[t][2];
        row[127] = T[t][127];
      }
    }
    __syncthreads();
  }

  // ---- mirror direction (off-diagonal tiles only) ----
  if (ti != tj) {
#pragma unroll
    for (int cn = 0; cn < 2; ++cn) {
#pragma unroll
      for (int nlo = 0; nlo < 2; ++nlo) {
        int n = cn * 2 + nlo;
        int jl = wc * 64 + n * 16 + lkb * 4;
        f32x4 sj = *(const f32x4*)&sqv[j0 + jl];
        int u0 = wc * 32 + nlo * 16 + lkb * 4;
#pragma unroll
        for (int m = 0; m < 4; ++m) {
          int il = wr * 64 + m * 16 + lrow;
          float si = sqv[i0 + il];
#pragma unroll
          for (int r = 0; r < 4; ++r) {
            float d2 = si + sj[r] - 2.f * acc[m][n][r];
            float dv = (d2 > 0.f) ? sqrtf(d2) : 0.f;
            T[u0 + r][il] = dv;  // transposed staging
          }
        }
      }
      __syncthreads();
      // rows gj, cols i0..i0+127
#pragma unroll
      for (int it = 0; it < 8; ++it) {
        int u = it * 8 + rgrp;
        int gj = j0 + (u >> 5) * 64 + cn * 32 + (u & 31);
        float* row = F + 5 + (size_t)gj * N_INST + i0;
        if (k < 31) {
          int jj = 3 + 4 * k;
          f32x4 v;
          v[0] = T[u][jj]; v[1] = T[u][jj + 1];
          v[2] = T[u][jj + 2]; v[3] = T[u][jj + 3];
          *(f32x4*)&row[jj] = v;
        } else {
          row[0] = T[u][0]; row[1] = T[u][1]; row[2] = T[u][2];
          row[127] = T[u][127];
        }
      }
      __syncthreads();
    }
  }
}

// ---- att logits -> exp, column sums --------------------------------------
__global__ __launch_bounds__(256) void attc_kernel(
    const float* __restrict__ h, const float* __restrict__ aW2,
    const float* __restrict__ ab2, float* __restrict__ exp_att,
    float* __restrict__ colsum) {
  __shared__ float csum[C_CLS];
  if (threadIdx.x < C_CLS) csum[threadIdx.x] = 0.f;
  __syncthreads();
  int i = blockIdx.x * 256 + threadIdx.x;  // 8192 rows
  float a[C_CLS];
#pragma unroll
  for (int c = 0; c < C_CLS; ++c) a[c] = ab2[c];
  const float* hr = h + (size_t)i * D_DIM;
  for (int d = 0; d < D_DIM; ++d) {
    float hv = hr[d];
#pragma unroll
    for (int c = 0; c < C_CLS; ++c) a[c] = fmaf(hv, aW2[d * C_CLS + c], a[c]);
  }
#pragma unroll
  for (int c = 0; c < C_CLS; ++c) {
    float e = expf(a[c]);
    exp_att[(size_t)i * C_CLS + c] = e;
    atomicAdd(&csum[c], e);
  }
  __syncthreads();
  if (threadIdx.x < C_CLS) atomicAdd(&colsum[threadIdx.x], csum[threadIdx.x]);
}

// ---- bagU[c][l] = sum_i exp_att[i][c] * x[i][l] --------------------------
__global__ __launch_bounds__(256) void bag_kernel(
    const float* __restrict__ x, const float* __restrict__ exp_att,
    float* __restrict__ bagU) {
  int t = threadIdx.x;
  int rbase = blockIdx.x * 32;
  float acc0[C_CLS] = {0, 0, 0, 0, 0}, acc1[C_CLS] = {0, 0, 0, 0, 0};
  int l0 = t, l1 = t + 256;  // l1 valid when t < 128
  for (int i = rbase; i < rbase + 32; ++i) {
    const float* xr = x + (size_t)i * L_DIM;
    float e[C_CLS];
#pragma unroll
    for (int c = 0; c < C_CLS; ++c) e[c] = exp_att[(size_t)i * C_CLS + c];
    float x0 = xr[l0];
#pragma unroll
    for (int c = 0; c < C_CLS; ++c) acc0[c] = fmaf(e[c], x0, acc0[c]);
    if (t < 128) {
      float x1 = xr[l1];
#pragma unroll
      for (int c = 0; c < C_CLS; ++c) acc1[c] = fmaf(e[c], x1, acc1[c]);
    }
  }
#pragma unroll
  for (int c = 0; c < C_CLS; ++c) atomicAdd(&bagU[c * L_DIM + l0], acc0[c]);
  if (t < 128)
#pragma unroll
    for (int c = 0; c < C_CLS; ++c) atomicAdd(&bagU[c * L_DIM + l1], acc1[c]);
}

// ---- final: normalize bag, per-class MLP head, write pred[0..4] ----------
__global__ __launch_bounds__(256) void final_kernel(
    const float* __restrict__ bagU, const float* __restrict__ colsum,
    const float* __restrict__ cW1, const float* __restrict__ cb1,
    const float* __restrict__ cW2, const float* __restrict__ cb2,
    float* __restrict__ out) {
  __shared__ float bag_s[C_CLS * L_DIM];
  __shared__ float h_s[C_CLS * 64];
  int t = threadIdx.x;
  for (int idx = t; idx < C_CLS * L_DIM; idx += 256) {
    int c = idx / L_DIM;
    bag_s[idx] = bagU[idx] / colsum[c];
  }
  __syncthreads();
  for (int idx = t; idx < C_CLS * 64; idx += 256) {
    int c = idx >> 6, hh = idx & 63;
    float acc = cb1[idx];
    for (int l = 0; l < L_DIM; ++l)
      acc = fmaf(bag_s[c * L_DIM + l], cW1[(size_t)(c * L_DIM + l) * 64 + hh], acc);
    h_s[idx] = fmaxf(acc, 0.f) * cW2[idx];
  }
  __syncthreads();
  if (t < C_CLS) {
    float p = cb2[t];
    for (int hh = 0; hh < 64; ++hh) p += h_s[t * 64 + hh];
    out[t] = p;
  }
}

extern "C" void kernel_launch(void* const* d_in, const int* in_sizes, int n_in,
                              void* d_out, int out_size, void* d_ws,
                              size_t ws_size, hipStream_t stream) {
  const float* x   = (const float*)d_in[0];
  const float* aW1 = (const float*)d_in[1];
  const float* ab1 = (const float*)d_in[2];
  const float* aW2 = (const float*)d_in[3];
  const float* ab2 = (const float*)d_in[4];
  const float* cW1 = (const float*)d_in[5];
  const float* cb1 = (const float*)d_in[6];
  const float* cW2 = (const float*)d_in[7];
  const float* cb2 = (const float*)d_in[8];
  float* outp = (float*)d_out;

  char* ws = (char*)d_ws;
  unsigned short* xbf = (unsigned short*)(ws);              // 6,291,456
  unsigned short* w1t = (unsigned short*)(ws + 6291456);    //    98,304
  float* sq           = (float*)(ws + 6389760);             //    32,768
  float* h_tanh       = (float*)(ws + 6422528);             // 4,194,304
  float* exp_att      = (float*)(ws + 10616832);            //   163,840
  float* colsum       = (float*)(ws + 10780672);            //        64
  float* bagU         = (float*)(ws + 10780736);            //     7,680

  hipMemsetAsync(ws + 10780672, 0, 64 + C_CLS * L_DIM * 4, stream);

  prep_x_kernel<<<2048, 256, 0, stream>>>(x, xbf, sq);
  prep_w_kernel<<<192, 256, 0, stream>>>(aW1, w1t);
  attn_gemm_kernel<<<64, 256, 0, stream>>>(xbf, w1t, ab1, h_tanh);
  attc_kernel<<<32, 256, 0, stream>>>(h_tanh, aW2, ab2, exp_att, colsum);
  bag_kernel<<<256, 256, 0, stream>>>(x, exp_att, bagU);
  final_kernel<<<1, 256, 0, stream>>>(bagU, colsum, cW1, cb1, cW2, cb2, outp);
  dist_kernel<<<2080, 256, 0, stream>>>(xbf, sq, outp);
}

// Round 4
// 214.067 us; speedup vs baseline: 1.0140x; 1.0140x over previous
//
#include <hip/hip_runtime.h>
#include <cstdint>
#include <cstddef>

#define N_INST 8192
#define L_DIM  384
#define D_DIM  128
#define C_CLS  5

typedef __bf16 bf16x8 __attribute__((ext_vector_type(8)));
typedef float  f32x4  __attribute__((ext_vector_type(4)));
// 4-byte-aligned float4 for the dist output (base offset 20 B).
typedef float  f32x4u __attribute__((ext_vector_type(4), aligned(4)));

typedef __attribute__((address_space(1))) void gvoid_t;
typedef __attribute__((address_space(3))) void lvoid_t;

__device__ __forceinline__ unsigned short f2bf(float f) {
  unsigned u = __float_as_uint(f);
  unsigned r = (u + 0x7FFFu + ((u >> 16) & 1u)) >> 16;  // RNE
  return (unsigned short)r;
}
__device__ __forceinline__ float bf2f(unsigned short b) {
  return __uint_as_float(((unsigned)b) << 16);
}

__device__ __forceinline__ void gload_lds16(const void* g, void* lds) {
  __builtin_amdgcn_global_load_lds(
      (gvoid_t*)(uintptr_t)g,
      (lvoid_t*)(uint32_t)(uintptr_t)lds,
      16, 0, 0);
}

// ---- prep: x -> bf16, sq[i] = sum(bf16(x_i)^2) in fp32 -------------------
__global__ __launch_bounds__(256) void prep_x_kernel(
    const float* __restrict__ x, unsigned short* __restrict__ xbf,
    float* __restrict__ sq) {
  int w = threadIdx.x >> 6, lane = threadIdx.x & 63;
  int row = blockIdx.x * 4 + w;
  const float* xr = x + (size_t)row * L_DIM;
  unsigned short* br = xbf + (size_t)row * L_DIM;
  float s = 0.f;
#pragma unroll
  for (int k = 0; k < 6; ++k) {
    float v = xr[lane + 64 * k];
    unsigned short b = f2bf(v);
    br[lane + 64 * k] = b;
    float vb = bf2f(b);
    s = fmaf(vb, vb, s);
  }
#pragma unroll
  for (int off = 32; off; off >>= 1) s += __shfl_down(s, off, 64);
  if (lane == 0) sq[row] = s;
}

// ---- prep: aW1 [384][128] -> aW1T_bf [128][384] --------------------------
__global__ __launch_bounds__(256) void prep_w_kernel(
    const float* __restrict__ aW1, unsigned short* __restrict__ w1t) {
  int idx = blockIdx.x * 256 + threadIdx.x;  // 49152 total
  int d = idx / L_DIM, l = idx - d * L_DIM;
  w1t[idx] = f2bf(aW1[(size_t)l * D_DIM + d]);
}

// ---- attention GEMM: h_tanh[i][d] = tanh(x_bf . aW1T[d] + ab1[d]) --------
__global__ __launch_bounds__(256, 2) void attn_gemm_kernel(
    const unsigned short* __restrict__ amat,   // x_bf [8192][384]
    const unsigned short* __restrict__ bmat,   // aW1T_bf [128][384]
    const float* __restrict__ bias,            // ab1
    float* __restrict__ out) {
  __shared__ alignas(16) unsigned short As[128][64];
  __shared__ alignas(16) unsigned short Bs[128][64];

  int tid = threadIdx.x;
  int w = tid >> 6, lane = tid & 63;
  int wr = w >> 1, wc = w & 1;
  int i0 = blockIdx.x * 128;

  const unsigned short* asrc = amat + (size_t)i0 * L_DIM;
  const unsigned short* bsrc = bmat;

  f32x4 acc[4][4];
#pragma unroll
  for (int m = 0; m < 4; ++m)
#pragma unroll
    for (int n = 0; n < 4; ++n) acc[m][n] = (f32x4){0.f, 0.f, 0.f, 0.f};

  int lrow = lane & 15, lkb = lane >> 4;

  for (int kc = 0; kc < 6; ++kc) {
    int k0 = kc * 64;
#pragma unroll
    for (int c = 0; c < 4; ++c) {
      int rb = c * 32 + w * 8;
      gload_lds16(asrc + (size_t)(rb + (lane >> 3)) * L_DIM + k0 + (lane & 7) * 8,
                  &As[rb][0]);
      gload_lds16(bsrc + (size_t)(rb + (lane >> 3)) * L_DIM + k0 + (lane & 7) * 8,
                  &Bs[rb][0]);
    }
    __syncthreads();
#pragma unroll
    for (int kk = 0; kk < 64; kk += 32) {
      bf16x8 af[4], bfr[4];
#pragma unroll
      for (int m = 0; m < 4; ++m)
        af[m] = *(const bf16x8*)&As[wr * 64 + m * 16 + lrow][kk + lkb * 8];
#pragma unroll
      for (int n = 0; n < 4; ++n)
        bfr[n] = *(const bf16x8*)&Bs[wc * 64 + n * 16 + lrow][kk + lkb * 8];
#pragma unroll
      for (int m = 0; m < 4; ++m)
#pragma unroll
        for (int n = 0; n < 4; ++n)
          acc[m][n] = __builtin_amdgcn_mfma_f32_16x16x32_bf16(
              bfr[n], af[m], acc[m][n], 0, 0, 0);  // swapped operands
    }
    __syncthreads();
  }
  // i = i0 + wr*64 + m*16 + lrow ; d = wc*64 + n*16 + lkb*4 + r
#pragma unroll
  for (int m = 0; m < 4; ++m) {
    int gi = i0 + wr * 64 + m * 16 + lrow;
    float* orow = out + (size_t)gi * D_DIM;
#pragma unroll
    for (int n = 0; n < 4; ++n) {
      int d0 = wc * 64 + n * 16 + lkb * 4;
      f32x4 bv = *(const f32x4*)&bias[d0];
      f32x4 o;
#pragma unroll
      for (int r = 0; r < 4; ++r) o[r] = tanhf(acc[m][n][r] + bv[r]);
      *(f32x4*)&orow[d0] = o;  // workspace, 16B aligned
    }
  }
}

// ---- dist GEMM: full grid, XCD-swizzled for write-seam L2 locality -------
// dist[i][j] = sqrt(max(sq_i+sq_j-2*dot,0)) at F[5 + i*8192 + j], diag = 0.
// acc[m][n][r] = dot(i,j): i = i0+wr*64+m*16+lrow ; j = j0+wc*64+n*16+lkb*4+r
__global__ __launch_bounds__(256, 2) void dist_kernel(
    const unsigned short* __restrict__ xbf, const float* __restrict__ sqv,
    float* __restrict__ F) {
  __shared__ alignas(16) unsigned short As[128][64];
  __shared__ alignas(16) unsigned short Bs[128][64];

  int tid = threadIdx.x;
  int w = tid >> 6, lane = tid & 63;
  int wr = w >> 1, wc = w & 1;

  // XCD swizzle (bijective, 4096 = 8*512): XCD k (= blockIdx%8 round-robin)
  // owns row-panels 8k..8k+7 with tj sequential in dispatch order, so the
  // partial-line seams between tj-neighbors merge in the same XCD's L2.
  int b = blockIdx.x;
  int bs = (b & 7) * 512 + (b >> 3);
  int ti = bs >> 6, tj = bs & 63;
  int i0 = ti * 128, j0 = tj * 128;

  const unsigned short* asrc = xbf + (size_t)i0 * L_DIM;
  const unsigned short* bsrc = xbf + (size_t)j0 * L_DIM;

  f32x4 acc[4][4];
#pragma unroll
  for (int m = 0; m < 4; ++m)
#pragma unroll
    for (int n = 0; n < 4; ++n) acc[m][n] = (f32x4){0.f, 0.f, 0.f, 0.f};

  int lrow = lane & 15, lkb = lane >> 4;

  for (int kc = 0; kc < 6; ++kc) {
    int k0 = kc * 64;
#pragma unroll
    for (int c = 0; c < 4; ++c) {
      int rb = c * 32 + w * 8;  // wave-uniform LDS base row
      gload_lds16(asrc + (size_t)(rb + (lane >> 3)) * L_DIM + k0 + (lane & 7) * 8,
                  &As[rb][0]);
      gload_lds16(bsrc + (size_t)(rb + (lane >> 3)) * L_DIM + k0 + (lane & 7) * 8,
                  &Bs[rb][0]);
    }
    __syncthreads();
#pragma unroll
    for (int kk = 0; kk < 64; kk += 32) {
      bf16x8 af[4], bfr[4];
#pragma unroll
      for (int m = 0; m < 4; ++m)
        af[m] = *(const bf16x8*)&As[wr * 64 + m * 16 + lrow][kk + lkb * 8];
#pragma unroll
      for (int n = 0; n < 4; ++n)
        bfr[n] = *(const bf16x8*)&Bs[wc * 64 + n * 16 + lrow][kk + lkb * 8];
#pragma unroll
      for (int m = 0; m < 4; ++m)
#pragma unroll
        for (int n = 0; n < 4; ++n)
          acc[m][n] = __builtin_amdgcn_mfma_f32_16x16x32_bf16(
              bfr[n], af[m], acc[m][n], 0, 0, 0);  // swapped operands
    }
    __syncthreads();
  }

  // epilogue: per (m,n) one contiguous float4 store per lane
#pragma unroll
  for (int m = 0; m < 4; ++m) {
    int gi = i0 + wr * 64 + m * 16 + lrow;
    float si = sqv[gi];
    float* orow = F + 5 + (size_t)gi * N_INST;
#pragma unroll
    for (int n = 0; n < 4; ++n) {
      int gjb = j0 + wc * 64 + n * 16 + lkb * 4;
      f32x4 sj = *(const f32x4*)&sqv[gjb];
      f32x4u o;
#pragma unroll
      for (int r = 0; r < 4; ++r) {
        float d2 = si + sj[r] - 2.f * acc[m][n][r];
        float dv = (d2 > 0.f) ? sqrtf(d2) : 0.f;
        if (gi == gjb + r) dv = 0.f;
        o[r] = dv;
      }
      *(f32x4u*)&orow[gjb] = o;
    }
  }
}

// ---- att logits -> exp, column sums --------------------------------------
__global__ __launch_bounds__(256) void attc_kernel(
    const float* __restrict__ h, const float* __restrict__ aW2,
    const float* __restrict__ ab2, float* __restrict__ exp_att,
    float* __restrict__ colsum) {
  __shared__ float csum[C_CLS];
  if (threadIdx.x < C_CLS) csum[threadIdx.x] = 0.f;
  __syncthreads();
  int i = blockIdx.x * 256 + threadIdx.x;  // 8192 rows
  float a[C_CLS];
#pragma unroll
  for (int c = 0; c < C_CLS; ++c) a[c] = ab2[c];
  const float* hr = h + (size_t)i * D_DIM;
  for (int d = 0; d < D_DIM; ++d) {
    float hv = hr[d];
#pragma unroll
    for (int c = 0; c < C_CLS; ++c) a[c] = fmaf(hv, aW2[d * C_CLS + c], a[c]);
  }
#pragma unroll
  for (int c = 0; c < C_CLS; ++c) {
    float e = expf(a[c]);
    exp_att[(size_t)i * C_CLS + c] = e;
    atomicAdd(&csum[c], e);
  }
  __syncthreads();
  if (threadIdx.x < C_CLS) atomicAdd(&colsum[threadIdx.x], csum[threadIdx.x]);
}

// ---- bagU[c][l] = sum_i exp_att[i][c] * x[i][l] --------------------------
__global__ __launch_bounds__(256) void bag_kernel(
    const float* __restrict__ x, const float* __restrict__ exp_att,
    float* __restrict__ bagU) {
  int t = threadIdx.x;
  int rbase = blockIdx.x * 32;
  float acc0[C_CLS] = {0, 0, 0, 0, 0}, acc1[C_CLS] = {0, 0, 0, 0, 0};
  int l0 = t, l1 = t + 256;  // l1 valid when t < 128
  for (int i = rbase; i < rbase + 32; ++i) {
    const float* xr = x + (size_t)i * L_DIM;
    float e[C_CLS];
#pragma unroll
    for (int c = 0; c < C_CLS; ++c) e[c] = exp_att[(size_t)i * C_CLS + c];
    float x0 = xr[l0];
#pragma unroll
    for (int c = 0; c < C_CLS; ++c) acc0[c] = fmaf(e[c], x0, acc0[c]);
    if (t < 128) {
      float x1 = xr[l1];
#pragma unroll
      for (int c = 0; c < C_CLS; ++c) acc1[c] = fmaf(e[c], x1, acc1[c]);
    }
  }
#pragma unroll
  for (int c = 0; c < C_CLS; ++c) atomicAdd(&bagU[c * L_DIM + l0], acc0[c]);
  if (t < 128)
#pragma unroll
    for (int c = 0; c < C_CLS; ++c) atomicAdd(&bagU[c * L_DIM + l1], acc1[c]);
}

// ---- final: normalize bag, per-class MLP head, write pred[0..4] ----------
__global__ __launch_bounds__(256) void final_kernel(
    const float* __restrict__ bagU, const float* __restrict__ colsum,
    const float* __restrict__ cW1, const float* __restrict__ cb1,
    const float* __restrict__ cW2, const float* __restrict__ cb2,
    float* __restrict__ out) {
  __shared__ float bag_s[C_CLS * L_DIM];
  __shared__ float h_s[C_CLS * 64];
  int t = threadIdx.x;
  for (int idx = t; idx < C_CLS * L_DIM; idx += 256) {
    int c = idx / L_DIM;
    bag_s[idx] = bagU[idx] / colsum[c];
  }
  __syncthreads();
  for (int idx = t; idx < C_CLS * 64; idx += 256) {
    int c = idx >> 6, hh = idx & 63;
    float acc = cb1[idx];
    for (int l = 0; l < L_DIM; ++l)
      acc = fmaf(bag_s[c * L_DIM + l], cW1[(size_t)(c * L_DIM + l) * 64 + hh], acc);
    h_s[idx] = fmaxf(acc, 0.f) * cW2[idx];
  }
  __syncthreads();
  if (t < C_CLS) {
    float p = cb2[t];
    for (int hh = 0; hh < 64; ++hh) p += h_s[t * 64 + hh];
    out[t] = p;
  }
}

extern "C" void kernel_launch(void* const* d_in, const int* in_sizes, int n_in,
                              void* d_out, int out_size, void* d_ws,
                              size_t ws_size, hipStream_t stream) {
  const float* x   = (const float*)d_in[0];
  const float* aW1 = (const float*)d_in[1];
  const float* ab1 = (const float*)d_in[2];
  const float* aW2 = (const float*)d_in[3];
  const float* ab2 = (const float*)d_in[4];
  const float* cW1 = (const float*)d_in[5];
  const float* cb1 = (const float*)d_in[6];
  const float* cW2 = (const float*)d_in[7];
  const float* cb2 = (const float*)d_in[8];
  float* outp = (float*)d_out;

  char* ws = (char*)d_ws;
  unsigned short* xbf = (unsigned short*)(ws);              // 6,291,456
  unsigned short* w1t = (unsigned short*)(ws + 6291456);    //    98,304
  float* sq           = (float*)(ws + 6389760);             //    32,768
  float* h_tanh       = (float*)(ws + 6422528);             // 4,194,304
  float* exp_att      = (float*)(ws + 10616832);            //   163,840
  float* colsum       = (float*)(ws + 10780672);            //        64
  float* bagU         = (float*)(ws + 10780736);            //     7,680

  hipMemsetAsync(ws + 10780672, 0, 64 + C_CLS * L_DIM * 4, stream);

  prep_x_kernel<<<2048, 256, 0, stream>>>(x, xbf, sq);
  prep_w_kernel<<<192, 256, 0, stream>>>(aW1, w1t);
  attn_gemm_kernel<<<64, 256, 0, stream>>>(xbf, w1t, ab1, h_tanh);
  attc_kernel<<<32, 256, 0, stream>>>(h_tanh, aW2, ab2, exp_att, colsum);
  bag_kernel<<<256, 256, 0, stream>>>(x, exp_att, bagU);
  final_kernel<<<1, 256, 0, stream>>>(bagU, colsum, cW1, cb1, cW2, cb2, outp);
  dist_kernel<<<4096, 256, 0, stream>>>(xbf, sq, outp);
}

// Round 5
// 189.411 us; speedup vs baseline: 1.1460x; 1.1302x over previous
//
#include <hip/hip_runtime.h>
#include <cstdint>
#include <cstddef>

#define N_INST 8192
#define L_DIM  384
#define D_DIM  128
#define C_CLS  5

typedef __bf16 bf16x8 __attribute__((ext_vector_type(8)));
typedef float  f32x4  __attribute__((ext_vector_type(4)));
// 4-byte-aligned float4 for the dist output (base offset 20 B).
typedef float  f32x4u __attribute__((ext_vector_type(4), aligned(4)));

typedef __attribute__((address_space(1))) void gvoid_t;
typedef __attribute__((address_space(3))) void lvoid_t;

__device__ __forceinline__ unsigned short f2bf(float f) {
  unsigned u = __float_as_uint(f);
  unsigned r = (u + 0x7FFFu + ((u >> 16) & 1u)) >> 16;  // RNE
  return (unsigned short)r;
}
__device__ __forceinline__ float bf2f(unsigned short b) {
  return __uint_as_float(((unsigned)b) << 16);
}

__device__ __forceinline__ void gload_lds16(const void* g, void* lds) {
  __builtin_amdgcn_global_load_lds(
      (gvoid_t*)(uintptr_t)g,
      (lvoid_t*)(uint32_t)(uintptr_t)lds,
      16, 0, 0);
}

// ---- prep: x -> bf16, sq[i] = sum(bf16(x_i)^2) in fp32 -------------------
__global__ __launch_bounds__(256) void prep_x_kernel(
    const float* __restrict__ x, unsigned short* __restrict__ xbf,
    float* __restrict__ sq) {
  int w = threadIdx.x >> 6, lane = threadIdx.x & 63;
  int row = blockIdx.x * 4 + w;
  const float* xr = x + (size_t)row * L_DIM;
  unsigned short* br = xbf + (size_t)row * L_DIM;
  float s = 0.f;
#pragma unroll
  for (int k = 0; k < 6; ++k) {
    float v = xr[lane + 64 * k];
    unsigned short b = f2bf(v);
    br[lane + 64 * k] = b;
    float vb = bf2f(b);
    s = fmaf(vb, vb, s);
  }
#pragma unroll
  for (int off = 32; off; off >>= 1) s += __shfl_down(s, off, 64);
  if (lane == 0) sq[row] = s;
}

// ---- prep: aW1 [384][128] -> aW1T_bf [128][384] --------------------------
__global__ __launch_bounds__(256) void prep_w_kernel(
    const float* __restrict__ aW1, unsigned short* __restrict__ w1t) {
  int idx = blockIdx.x * 256 + threadIdx.x;  // 49152 total
  int d = idx / L_DIM, l = idx - d * L_DIM;
  w1t[idx] = f2bf(aW1[(size_t)l * D_DIM + d]);
}

// ---- attention GEMM: h_tanh[i][d] = tanh(x_bf . aW1T[d] + ab1[d]) --------
__global__ __launch_bounds__(256, 2) void attn_gemm_kernel(
    const unsigned short* __restrict__ amat,   // x_bf [8192][384]
    const unsigned short* __restrict__ bmat,   // aW1T_bf [128][384]
    const float* __restrict__ bias,            // ab1
    float* __restrict__ out) {
  __shared__ alignas(16) unsigned short As[128][64];
  __shared__ alignas(16) unsigned short Bs[128][64];

  int tid = threadIdx.x;
  int w = tid >> 6, lane = tid & 63;
  int wr = w >> 1, wc = w & 1;
  int i0 = blockIdx.x * 128;

  const unsigned short* asrc = amat + (size_t)i0 * L_DIM;
  const unsigned short* bsrc = bmat;

  f32x4 acc[4][4];
#pragma unroll
  for (int m = 0; m < 4; ++m)
#pragma unroll
    for (int n = 0; n < 4; ++n) acc[m][n] = (f32x4){0.f, 0.f, 0.f, 0.f};

  int lrow = lane & 15, lkb = lane >> 4;

  for (int kc = 0; kc < 6; ++kc) {
    int k0 = kc * 64;
#pragma unroll
    for (int c = 0; c < 4; ++c) {
      int rb = c * 32 + w * 8;
      gload_lds16(asrc + (size_t)(rb + (lane >> 3)) * L_DIM + k0 + (lane & 7) * 8,
                  &As[rb][0]);
      gload_lds16(bsrc + (size_t)(rb + (lane >> 3)) * L_DIM + k0 + (lane & 7) * 8,
                  &Bs[rb][0]);
    }
    __syncthreads();
#pragma unroll
    for (int kk = 0; kk < 64; kk += 32) {
      bf16x8 af[4], bfr[4];
#pragma unroll
      for (int m = 0; m < 4; ++m)
        af[m] = *(const bf16x8*)&As[wr * 64 + m * 16 + lrow][kk + lkb * 8];
#pragma unroll
      for (int n = 0; n < 4; ++n)
        bfr[n] = *(const bf16x8*)&Bs[wc * 64 + n * 16 + lrow][kk + lkb * 8];
#pragma unroll
      for (int m = 0; m < 4; ++m)
#pragma unroll
        for (int n = 0; n < 4; ++n)
          acc[m][n] = __builtin_amdgcn_mfma_f32_16x16x32_bf16(
              bfr[n], af[m], acc[m][n], 0, 0, 0);  // swapped operands
    }
    __syncthreads();
  }
  // i = i0 + wr*64 + m*16 + lrow ; d = wc*64 + n*16 + lkb*4 + r
#pragma unroll
  for (int m = 0; m < 4; ++m) {
    int gi = i0 + wr * 64 + m * 16 + lrow;
    float* orow = out + (size_t)gi * D_DIM;
#pragma unroll
    for (int n = 0; n < 4; ++n) {
      int d0 = wc * 64 + n * 16 + lkb * 4;
      f32x4 bv = *(const f32x4*)&bias[d0];
      f32x4 o;
#pragma unroll
      for (int r = 0; r < 4; ++r) o[r] = tanhf(acc[m][n][r] + bv[r]);
      *(f32x4*)&orow[d0] = o;  // workspace, 16B aligned
    }
  }
}

// ---- dist GEMM: full grid, T2 XOR-swizzled LDS ---------------------------
// dist[i][j] = sqrt(max(sq_i+sq_j-2*dot,0)) at F[5 + i*8192 + j], diag = 0.
// acc[m][n][r] = dot(i,j): i = i0+wr*64+m*16+lrow ; j = j0+wc*64+n*16+lkb*4+r
//
// LDS swizzle (rule #21, both-sides involution at 16B-chunk granularity):
//   physical slot (row, chunk) holds global (row, chunk ^ (row&7)).
//   - stage: LDS dest linear (global_load_lds); per-lane GLOBAL source
//     chunk = (lane&7) ^ (lane>>3)   [staged base rows are multiples of 8,
//     so row&7 == lane>>3]
//   - read: logical col c at row -> physical c ^ ((row&7)<<3); fragment
//     rows have row&7 == lane&7.
// Breaks the 16-lane same-bank column read (128B row stride) -> <=2
// lanes/bank.
__global__ __launch_bounds__(256, 2) void dist_kernel(
    const unsigned short* __restrict__ xbf, const float* __restrict__ sqv,
    float* __restrict__ F) {
  __shared__ alignas(16) unsigned short As[128][64];
  __shared__ alignas(16) unsigned short Bs[128][64];

  int tid = threadIdx.x;
  int w = tid >> 6, lane = tid & 63;
  int wr = w >> 1, wc = w & 1;

  int b = blockIdx.x;
  int ti = b >> 6, tj = b & 63;
  int i0 = ti * 128, j0 = tj * 128;

  const unsigned short* asrc = xbf + (size_t)i0 * L_DIM;
  const unsigned short* bsrc = xbf + (size_t)j0 * L_DIM;

  f32x4 acc[4][4];
#pragma unroll
  for (int m = 0; m < 4; ++m)
#pragma unroll
    for (int n = 0; n < 4; ++n) acc[m][n] = (f32x4){0.f, 0.f, 0.f, 0.f};

  int lrow = lane & 15, lkb = lane >> 4;
  int schunk = ((lane & 7) ^ (lane >> 3)) * 8;  // pre-swizzled source chunk
  int swz = (lane & 7) << 3;                    // read-side xor (row&7 == lane&7)

  for (int kc = 0; kc < 6; ++kc) {
    int k0 = kc * 64;
#pragma unroll
    for (int c = 0; c < 4; ++c) {
      int rb = c * 32 + w * 8;  // wave-uniform LDS base row (rb % 8 == 0)
      gload_lds16(asrc + (size_t)(rb + (lane >> 3)) * L_DIM + k0 + schunk,
                  &As[rb][0]);
      gload_lds16(bsrc + (size_t)(rb + (lane >> 3)) * L_DIM + k0 + schunk,
                  &Bs[rb][0]);
    }
    __syncthreads();
#pragma unroll
    for (int kk = 0; kk < 64; kk += 32) {
      bf16x8 af[4], bfr[4];
#pragma unroll
      for (int m = 0; m < 4; ++m)
        af[m] = *(const bf16x8*)&As[wr * 64 + m * 16 + lrow][(kk + lkb * 8) ^ swz];
#pragma unroll
      for (int n = 0; n < 4; ++n)
        bfr[n] = *(const bf16x8*)&Bs[wc * 64 + n * 16 + lrow][(kk + lkb * 8) ^ swz];
#pragma unroll
      for (int m = 0; m < 4; ++m)
#pragma unroll
        for (int n = 0; n < 4; ++n)
          acc[m][n] = __builtin_amdgcn_mfma_f32_16x16x32_bf16(
              bfr[n], af[m], acc[m][n], 0, 0, 0);  // swapped operands
    }
    __syncthreads();
  }

  // epilogue: per (m,n) one contiguous float4 store per lane
#pragma unroll
  for (int m = 0; m < 4; ++m) {
    int gi = i0 + wr * 64 + m * 16 + lrow;
    float si = sqv[gi];
    float* orow = F + 5 + (size_t)gi * N_INST;
#pragma unroll
    for (int n = 0; n < 4; ++n) {
      int gjb = j0 + wc * 64 + n * 16 + lkb * 4;
      f32x4 sj = *(const f32x4*)&sqv[gjb];
      f32x4u o;
#pragma unroll
      for (int r = 0; r < 4; ++r) {
        float d2 = si + sj[r] - 2.f * acc[m][n][r];
        float dv = (d2 > 0.f) ? sqrtf(d2) : 0.f;
        if (gi == gjb + r) dv = 0.f;
        o[r] = dv;
      }
      *(f32x4u*)&orow[gjb] = o;
    }
  }
}

// ---- att logits -> exp, column sums --------------------------------------
__global__ __launch_bounds__(256) void attc_kernel(
    const float* __restrict__ h, const float* __restrict__ aW2,
    const float* __restrict__ ab2, float* __restrict__ exp_att,
    float* __restrict__ colsum) {
  __shared__ float csum[C_CLS];
  if (threadIdx.x < C_CLS) csum[threadIdx.x] = 0.f;
  __syncthreads();
  int i = blockIdx.x * 256 + threadIdx.x;  // 8192 rows
  float a[C_CLS];
#pragma unroll
  for (int c = 0; c < C_CLS; ++c) a[c] = ab2[c];
  const float* hr = h + (size_t)i * D_DIM;
  for (int d = 0; d < D_DIM; ++d) {
    float hv = hr[d];
#pragma unroll
    for (int c = 0; c < C_CLS; ++c) a[c] = fmaf(hv, aW2[d * C_CLS + c], a[c]);
  }
#pragma unroll
  for (int c = 0; c < C_CLS; ++c) {
    float e = expf(a[c]);
    exp_att[(size_t)i * C_CLS + c] = e;
    atomicAdd(&csum[c], e);
  }
  __syncthreads();
  if (threadIdx.x < C_CLS) atomicAdd(&colsum[threadIdx.x], csum[threadIdx.x]);
}

// ---- bagU[c][l] = sum_i exp_att[i][c] * x[i][l] --------------------------
__global__ __launch_bounds__(256) void bag_kernel(
    const float* __restrict__ x, const float* __restrict__ exp_att,
    float* __restrict__ bagU) {
  int t = threadIdx.x;
  int rbase = blockIdx.x * 32;
  float acc0[C_CLS] = {0, 0, 0, 0, 0}, acc1[C_CLS] = {0, 0, 0, 0, 0};
  int l0 = t, l1 = t + 256;  // l1 valid when t < 128
  for (int i = rbase; i < rbase + 32; ++i) {
    const float* xr = x + (size_t)i * L_DIM;
    float e[C_CLS];
#pragma unroll
    for (int c = 0; c < C_CLS; ++c) e[c] = exp_att[(size_t)i * C_CLS + c];
    float x0 = xr[l0];
#pragma unroll
    for (int c = 0; c < C_CLS; ++c) acc0[c] = fmaf(e[c], x0, acc0[c]);
    if (t < 128) {
      float x1 = xr[l1];
#pragma unroll
      for (int c = 0; c < C_CLS; ++c) acc1[c] = fmaf(e[c], x1, acc1[c]);
    }
  }
#pragma unroll
  for (int c = 0; c < C_CLS; ++c) atomicAdd(&bagU[c * L_DIM + l0], acc0[c]);
  if (t < 128)
#pragma unroll
    for (int c = 0; c < C_CLS; ++c) atomicAdd(&bagU[c * L_DIM + l1], acc1[c]);
}

// ---- final: normalize bag, per-class MLP head, write pred[0..4] ----------
__global__ __launch_bounds__(256) void final_kernel(
    const float* __restrict__ bagU, const float* __restrict__ colsum,
    const float* __restrict__ cW1, const float* __restrict__ cb1,
    const float* __restrict__ cW2, const float* __restrict__ cb2,
    float* __restrict__ out) {
  __shared__ float bag_s[C_CLS * L_DIM];
  __shared__ float h_s[C_CLS * 64];
  int t = threadIdx.x;
  for (int idx = t; idx < C_CLS * L_DIM; idx += 256) {
    int c = idx / L_DIM;
    bag_s[idx] = bagU[idx] / colsum[c];
  }
  __syncthreads();
  for (int idx = t; idx < C_CLS * 64; idx += 256) {
    int c = idx >> 6, hh = idx & 63;
    float acc = cb1[idx];
    for (int l = 0; l < L_DIM; ++l)
      acc = fmaf(bag_s[c * L_DIM + l], cW1[(size_t)(c * L_DIM + l) * 64 + hh], acc);
    h_s[idx] = fmaxf(acc, 0.f) * cW2[idx];
  }
  __syncthreads();
  if (t < C_CLS) {
    float p = cb2[t];
    for (int hh = 0; hh < 64; ++hh) p += h_s[t * 64 + hh];
    out[t] = p;
  }
}

extern "C" void kernel_launch(void* const* d_in, const int* in_sizes, int n_in,
                              void* d_out, int out_size, void* d_ws,
                              size_t ws_size, hipStream_t stream) {
  const float* x   = (const float*)d_in[0];
  const float* aW1 = (const float*)d_in[1];
  const float* ab1 = (const float*)d_in[2];
  const float* aW2 = (const float*)d_in[3];
  const float* ab2 = (const float*)d_in[4];
  const float* cW1 = (const float*)d_in[5];
  const float* cb1 = (const float*)d_in[6];
  const float* cW2 = (const float*)d_in[7];
  const float* cb2 = (const float*)d_in[8];
  float* outp = (float*)d_out;

  char* ws = (char*)d_ws;
  unsigned short* xbf = (unsigned short*)(ws);              // 6,291,456
  unsigned short* w1t = (unsigned short*)(ws + 6291456);    //    98,304
  float* sq           = (float*)(ws + 6389760);             //    32,768
  float* h_tanh       = (float*)(ws + 6422528);             // 4,194,304
  float* exp_att      = (float*)(ws + 10616832);            //   163,840
  float* colsum       = (float*)(ws + 10780672);            //        64
  float* bagU         = (float*)(ws + 10780736);            //     7,680

  hipMemsetAsync(ws + 10780672, 0, 64 + C_CLS * L_DIM * 4, stream);

  prep_x_kernel<<<2048, 256, 0, stream>>>(x, xbf, sq);
  prep_w_kernel<<<192, 256, 0, stream>>>(aW1, w1t);
  attn_gemm_kernel<<<64, 256, 0, stream>>>(xbf, w1t, ab1, h_tanh);
  attc_kernel<<<32, 256, 0, stream>>>(h_tanh, aW2, ab2, exp_att, colsum);
  bag_kernel<<<256, 256, 0, stream>>>(x, exp_att, bagU);
  final_kernel<<<1, 256, 0, stream>>>(bagU, colsum, cW1, cb1, cW2, cb2, outp);
  dist_kernel<<<4096, 256, 0, stream>>>(xbf, sq, outp);
}